// Round 7
// baseline (88364.374 us; speedup 1.0000x reference)
//
#include <hip/hip_runtime.h>
#include <cstdint>
#include <cstddef>

#define VOCAB_N 50257
#define NPAD    50304          // padded row stride for logits (393 * 128)
#define DIM     1024
#define BSZ_N   32
#define BEAM_N  4
#define BB      128            // BSZ * BEAM
#define L_N     66             // MAXLEN + 2
#define SLEN_N  65             // MAXLEN + 1
#define MAXLEN_N 64
#define PAD_T   1
#define EOS_T   2
#define NEGV    (-1e9f)
#define SENTV   (-3.402823466e38f)
#define PW_BLOCK 128

// ---------------- compile-time numpy pairwise_sum tree ----------------
struct PWTree {
    int nleaf, nint, maxlev, root;
    int lstart[1024], lnum[1024], lslot[1024];
    int eL[1024], eR[1024], eD[1024];
    int lvl[32];
};

constexpr PWTree build_tree() {
    PWTree t{};
    int fs[64] = {}, fn[64] = {}, fstt[64] = {}, fls[64] = {}, fll[64] = {};
    int tL[1024] = {}, tR[1024] = {}, tD[1024] = {}, tLev[1024] = {};
    int sp = 0, lc = 0, nc = 0, cnt = 0;
    fs[0] = 0; fn[0] = VOCAB_N; fstt[0] = 0; sp = 1;
    int retslot = -1, retlev = 0;
    while (sp > 0) {
        const int n = fn[sp - 1], s = fs[sp - 1], st = fstt[sp - 1];
        if (n <= PW_BLOCK) {
            t.lstart[lc] = s; t.lnum[lc] = n; t.lslot[lc] = cnt;
            retslot = cnt; retlev = 0; ++cnt; ++lc; --sp; continue;
        }
        int L = (n >> 1); L -= (L & 7);
        if (st == 0)      { fstt[sp - 1] = 1; fs[sp] = s;     fn[sp] = L;     fstt[sp] = 0; ++sp; }
        else if (st == 1) { fls[sp - 1] = retslot; fll[sp - 1] = retlev; fstt[sp - 1] = 2;
                            fs[sp] = s + L; fn[sp] = n - L; fstt[sp] = 0; ++sp; }
        else {
            const int lv = (fll[sp - 1] > retlev ? fll[sp - 1] : retlev) + 1;
            tL[nc] = fls[sp - 1]; tR[nc] = retslot; tD[nc] = cnt; tLev[nc] = lv;
            retslot = cnt; retlev = lv; ++cnt; ++nc; --sp;
        }
    }
    int maxlev = 0;
    for (int j = 0; j < nc; ++j) if (tLev[j] > maxlev) maxlev = tLev[j];
    int cl[40] = {};
    for (int j = 0; j < nc; ++j) cl[tLev[j]]++;
    int acc = 0;
    for (int v = 1; v <= maxlev; ++v) { t.lvl[v] = acc; acc += cl[v]; }
    t.lvl[maxlev + 1] = acc;
    int pos[40] = {};
    for (int v = 1; v <= maxlev; ++v) pos[v] = t.lvl[v];
    for (int j = 0; j < nc; ++j) {
        const int v = tLev[j]; const int p = pos[v]++;
        t.eL[p] = tL[j]; t.eR[p] = tR[j]; t.eD[p] = tD[j];
    }
    t.nleaf = lc; t.nint = nc; t.maxlev = maxlev; t.root = retslot;
    return t;
}

__device__ constexpr PWTree g_tree = build_tree();

// ---------------- init state ----------------
__global__ void k_init(int* __restrict__ tokens, float* __restrict__ scores,
                       int* __restrict__ fin_tok, float* __restrict__ fin_sc) {
    int i = blockIdx.x * blockDim.x + threadIdx.x;
    int st = gridDim.x * blockDim.x;
    for (int k = i; k < BB * L_N; k += st) tokens[k] = ((k % L_N) == 0) ? EOS_T : PAD_T;
    for (int k = i; k < BB * SLEN_N; k += st) scores[k] = 0.f;
    for (int k = i; k < BB * L_N; k += st) fin_tok[k] = 0;
    for (int k = i; k < BB; k += st) fin_sc[k] = NEGV;
}

// ---------------- GEMM 128x128 tile, 8x8/thread, double-buffered LDS (r1-certified chain) ----------------
#define KSTEP 16
__global__ __launch_bounds__(256, 2) void k_gemm(const float* __restrict__ W,
                                                 const float* __restrict__ emb,
                                                 const float* __restrict__ pos_emb,
                                                 const int* __restrict__ tokens,
                                                 float* __restrict__ logits, int step) {
    __shared__ __align__(16) float Hs[2][KSTEP][128];    // 16 KB
    __shared__ __align__(16) float WsP[2][KSTEP][192];   // 24 KB: 16 groups x 8 floats @ stride 12
    const int tid = threadIdx.x;
    const int n0 = blockIdx.x * 128;
    const int cg  = tid & 15;          // col group (8 cols)
    const int m8  = (tid >> 4) * 8;    // row group (8 rows)
    const int c12 = cg * 12;
    const int lr  = tid >> 4;          // k-row for W staging
    const int mH  = tid >> 1;          // H staging row
    const int j0  = (tid & 1) * 8;     // H staging k-offset
    const int tokH = tokens[mH * L_N + step];
    const float* eprow = emb + (size_t)tokH * DIM;
    const float* pprow = pos_emb + (size_t)step * DIM;
    const int nb = n0 + cg * 8;
    const bool full = (n0 + 128 <= VOCAB_N);

    float acc[8][8];
#pragma unroll
    for (int i = 0; i < 8; ++i)
#pragma unroll
        for (int j = 0; j < 8; ++j) acc[i][j] = 0.f;

    float4 wA, wB, e0, e1, p0, p1;

    // ---- prologue: load + stage tile 0 ----
    {
        const float* wp = W + (size_t)lr * VOCAB_N + nb;
        if (full) { wA = *(const float4*)wp; wB = *(const float4*)(wp + 4); }
        else {
            wA.x = (nb + 0 < VOCAB_N) ? wp[0] : 0.f;
            wA.y = (nb + 1 < VOCAB_N) ? wp[1] : 0.f;
            wA.z = (nb + 2 < VOCAB_N) ? wp[2] : 0.f;
            wA.w = (nb + 3 < VOCAB_N) ? wp[3] : 0.f;
            wB.x = (nb + 4 < VOCAB_N) ? wp[4] : 0.f;
            wB.y = (nb + 5 < VOCAB_N) ? wp[5] : 0.f;
            wB.z = (nb + 6 < VOCAB_N) ? wp[6] : 0.f;
            wB.w = (nb + 7 < VOCAB_N) ? wp[7] : 0.f;
        }
        e0 = *(const float4*)(eprow + j0); e1 = *(const float4*)(eprow + j0 + 4);
        p0 = *(const float4*)(pprow + j0); p1 = *(const float4*)(pprow + j0 + 4);
        *(float4*)&WsP[0][lr][c12]     = wA;
        *(float4*)&WsP[0][lr][c12 + 4] = wB;
        Hs[0][j0 + 0][mH] = e0.x + p0.x; Hs[0][j0 + 1][mH] = e0.y + p0.y;
        Hs[0][j0 + 2][mH] = e0.z + p0.z; Hs[0][j0 + 3][mH] = e0.w + p0.w;
        Hs[0][j0 + 4][mH] = e1.x + p1.x; Hs[0][j0 + 5][mH] = e1.y + p1.y;
        Hs[0][j0 + 6][mH] = e1.z + p1.z; Hs[0][j0 + 7][mH] = e1.w + p1.w;
    }
    __syncthreads();

    const int NT = DIM / KSTEP;   // 64 K-tiles
    for (int t = 0; t < NT; ++t) {
        const int cur = t & 1;
        // ---- issue next tile's global loads (latency hides under FMAs) ----
        if (t + 1 < NT) {
            const int k0n = (t + 1) * KSTEP;
            const float* wp = W + (size_t)(k0n + lr) * VOCAB_N + nb;
            if (full) { wA = *(const float4*)wp; wB = *(const float4*)(wp + 4); }
            else {
                wA.x = (nb + 0 < VOCAB_N) ? wp[0] : 0.f;
                wA.y = (nb + 1 < VOCAB_N) ? wp[1] : 0.f;
                wA.z = (nb + 2 < VOCAB_N) ? wp[2] : 0.f;
                wA.w = (nb + 3 < VOCAB_N) ? wp[3] : 0.f;
                wB.x = (nb + 4 < VOCAB_N) ? wp[4] : 0.f;
                wB.y = (nb + 5 < VOCAB_N) ? wp[5] : 0.f;
                wB.z = (nb + 6 < VOCAB_N) ? wp[6] : 0.f;
                wB.w = (nb + 7 < VOCAB_N) ? wp[7] : 0.f;
            }
            const float* ep = eprow + k0n + j0;
            const float* pp = pprow + k0n + j0;
            e0 = *(const float4*)ep; e1 = *(const float4*)(ep + 4);
            p0 = *(const float4*)pp; p1 = *(const float4*)(pp + 4);
        }
        // ---- compute on LDS[cur] ----
#pragma unroll
        for (int kk = 0; kk < KSTEP; ++kk) {
            const float4 w0 = *(const float4*)&WsP[cur][kk][c12];
            const float4 w1 = *(const float4*)&WsP[cur][kk][c12 + 4];
            const float4 h0 = *(const float4*)&Hs[cur][kk][m8];
            const float4 h1 = *(const float4*)&Hs[cur][kk][m8 + 4];
            const float hh[8] = {h0.x, h0.y, h0.z, h0.w, h1.x, h1.y, h1.z, h1.w};
            const float ww[8] = {w0.x, w0.y, w0.z, w0.w, w1.x, w1.y, w1.z, w1.w};
#pragma unroll
            for (int i = 0; i < 8; ++i)
#pragma unroll
                for (int j = 0; j < 8; ++j)
                    acc[i][j] += hh[i] * ww[j];     // k-ascending f32 FMA chain (certified)
        }
        // ---- write next tile into the other buffer ----
        if (t + 1 < NT) {
            const int nxt = cur ^ 1;
            *(float4*)&WsP[nxt][lr][c12]     = wA;
            *(float4*)&WsP[nxt][lr][c12 + 4] = wB;
            Hs[nxt][j0 + 0][mH] = e0.x + p0.x; Hs[nxt][j0 + 1][mH] = e0.y + p0.y;
            Hs[nxt][j0 + 2][mH] = e0.z + p0.z; Hs[nxt][j0 + 3][mH] = e0.w + p0.w;
            Hs[nxt][j0 + 4][mH] = e1.x + p1.x; Hs[nxt][j0 + 5][mH] = e1.y + p1.y;
            Hs[nxt][j0 + 6][mH] = e1.z + p1.z; Hs[nxt][j0 + 7][mH] = e1.w + p1.w;
        }
        __syncthreads();
    }
#pragma unroll
    for (int i = 0; i < 8; ++i) {
        float4 o0; o0.x = acc[i][0]; o0.y = acc[i][1]; o0.z = acc[i][2]; o0.w = acc[i][3];
        float4 o1; o1.x = acc[i][4]; o1.y = acc[i][5]; o1.z = acc[i][6]; o1.w = acc[i][7];
        float* dst = &logits[(size_t)(m8 + i) * NPAD + nb];
        *(float4*)dst = o0;
        *(float4*)(dst + 4) = o1;
    }
}

// ---------------- packed (x, idx) keys: strict total order, stable ties ----------------
__device__ __forceinline__ unsigned sortable_f32(float x) {
    unsigned u = __float_as_uint(x);
    return (u & 0x80000000u) ? ~u : (u | 0x80000000u);
}
__device__ __forceinline__ float unsort_f32(unsigned s) {
    unsigned u = (s & 0x80000000u) ? (s & 0x7fffffffu) : ~s;
    return __uint_as_float(u);
}
__device__ __forceinline__ unsigned long long pack_key(float x, int tk) {
    return ((unsigned long long)sortable_f32(x) << 32) | (unsigned)(VOCAB_N - tk);
}
__device__ __forceinline__ void insk16(unsigned long long k, unsigned long long lst[16]) {
#pragma unroll
    for (int p = 0; p < 16; ++p) {
        if (k > lst[p]) { unsigned long long o = lst[p]; lst[p] = k; k = o; }
    }
}
__device__ __forceinline__ unsigned long long wave_max_u64(unsigned long long v) {
#pragma unroll
    for (int o = 32; o > 0; o >>= 1) {
        unsigned long long w = __shfl_xor(v, o, 64);
        if (w > v) v = w;
    }
    return v;
}

// ---------------- per-row: top16 (excl PAD) + max (incl PAD) + numpy-exact pairwise LSE ----------------
#define RT_THR 512
__global__ __launch_bounds__(RT_THR) void k_rowtop(const float* __restrict__ logits,
                                                   float* __restrict__ cand_x,
                                                   int* __restrict__ cand_ix,
                                                   float* __restrict__ rmax,
                                                   float* __restrict__ rlse) {
    const int row = blockIdx.x, tid = threadIdx.x;
    const int lane = tid & 63, wid = tid >> 6;   // 8 waves
    const float* x = logits + (size_t)row * NPAD;

    // ---- scan: per-thread top-16 (excluding PAD) + running max (including PAD) ----
    unsigned long long lst[16];
#pragma unroll
    for (int p = 0; p < 16; ++p) lst[p] = 0ULL;
    float mAll = SENTV;
    for (int v = tid * 4; v + 3 < VOCAB_N; v += RT_THR * 4) {
        const float4 t = *(const float4*)(x + v);
        mAll = fmaxf(mAll, fmaxf(fmaxf(t.x, t.y), fmaxf(t.z, t.w)));
        const float va[4] = {t.x, t.y, t.z, t.w};
#pragma unroll
        for (int u = 0; u < 4; ++u) {
            const int tk = v + u;
            if (tk == PAD_T) continue;
            const unsigned long long key = pack_key(va[u], tk);
            if (key > lst[15]) insk16(key, lst);
        }
    }
    if (tid == 0) {
        const int tk = VOCAB_N - 1;
        mAll = fmaxf(mAll, x[tk]);
        const unsigned long long key = pack_key(x[tk], tk);
        if (key > lst[15]) insk16(key, lst);
    }

    // ---- block max (includes PAD) ----
#pragma unroll
    for (int o = 32; o > 0; o >>= 1) mAll = fmaxf(mAll, __shfl_xor(mAll, o, 64));
    __shared__ float smx[8];
    if (lane == 0) smx[wid] = mAll;

    // ---- stage 1: per-wave top-16 via shfl tournament (no barriers) ----
    __shared__ unsigned long long wtop[8][16];
    for (int pass = 0; pass < 16; ++pass) {
        const unsigned long long cand = lst[0];
        const unsigned long long mx = wave_max_u64(cand);
        const unsigned long long ball = __ballot(cand == mx);
        const int first = __ffsll((unsigned long long)ball) - 1;
        if (lane == first) {
#pragma unroll
            for (int p = 0; p < 15; ++p) lst[p] = lst[p + 1];
            lst[15] = 0ULL;
        }
        if (lane == 0) wtop[wid][pass] = mx;
    }
    __syncthreads();

    // ---- stage 2: wave 0 merges 8x16 = 128 keys -> global top-16 ----
    __shared__ unsigned long long sfin[16];
    if (tid < 64) {
        unsigned long long a = wtop[tid >> 3][(tid & 7) * 2];      // descending pair: a >= b
        unsigned long long b = wtop[tid >> 3][(tid & 7) * 2 + 1];
        for (int pass = 0; pass < 16; ++pass) {
            const unsigned long long mx = wave_max_u64(a);
            const unsigned long long ball = __ballot(a == mx);
            const int first = __ffsll((unsigned long long)ball) - 1;
            if (tid == first) { a = b; b = 0ULL; }
            if (tid == 0) sfin[pass] = mx;
        }
    }
    __syncthreads();
    const float mrow = fmaxf(fmaxf(fmaxf(smx[0], smx[1]), fmaxf(smx[2], smx[3])),
                             fmaxf(fmaxf(smx[4], smx[5]), fmaxf(smx[6], smx[7])));

    // ---- numpy pairwise exp-sum via compile-time tree (bit-exact r3/r4 structure) ----
    __shared__ float slot[2048];
    const int nleaf = g_tree.nleaf, maxlev = g_tree.maxlev;
    for (int leaf = tid; leaf < nleaf; leaf += RT_THR) {
        const int s = g_tree.lstart[leaf];
        const int n = g_tree.lnum[leaf];
        float res;
        if (n < 8) {
            res = 0.f;
            for (int i = 0; i < n; ++i) res += expf(x[s + i] - mrow);
        } else {
            float r0 = expf(x[s + 0] - mrow), r1 = expf(x[s + 1] - mrow);
            float r2 = expf(x[s + 2] - mrow), r3 = expf(x[s + 3] - mrow);
            float r4 = expf(x[s + 4] - mrow), r5 = expf(x[s + 5] - mrow);
            float r6 = expf(x[s + 6] - mrow), r7 = expf(x[s + 7] - mrow);
            int i = 8;
            const int lim = n - (n & 7);
            for (; i < lim; i += 8) {
                r0 += expf(x[s + i + 0] - mrow); r1 += expf(x[s + i + 1] - mrow);
                r2 += expf(x[s + i + 2] - mrow); r3 += expf(x[s + i + 3] - mrow);
                r4 += expf(x[s + i + 4] - mrow); r5 += expf(x[s + i + 5] - mrow);
                r6 += expf(x[s + i + 6] - mrow); r7 += expf(x[s + i + 7] - mrow);
            }
            res = ((r0 + r1) + (r2 + r3)) + ((r4 + r5) + (r6 + r7));
            for (; i < n; ++i) res += expf(x[s + i] - mrow);
        }
        slot[g_tree.lslot[leaf]] = res;
    }
    __syncthreads();
    for (int lev = 1; lev <= maxlev; ++lev) {
        for (int j = g_tree.lvl[lev] + tid; j < g_tree.lvl[lev + 1]; j += RT_THR)
            slot[g_tree.eD[j]] = slot[g_tree.eL[j]] + slot[g_tree.eR[j]];
        __syncthreads();
    }
    if (tid == 0) {
        rmax[row] = mrow;
        rlse[row] = (float)log((double)slot[g_tree.root]);
    }
    if (tid < 16) {
        const unsigned long long k = sfin[tid];
        cand_x[row * 16 + tid]  = unsort_f32((unsigned)(k >> 32));
        cand_ix[row * 16 + tid] = VOCAB_N - (int)(k & 0xFFFFFFFFu);
    }
}

// ---------------- per-sentence: candidate vals + top-8 + literal bookkeeping ----------------
__global__ __launch_bounds__(256) void k_beam(const float* __restrict__ cand_x,
                                              const int* __restrict__ cand_ix,
                                              const float* __restrict__ rmax,
                                              const float* __restrict__ rlse,
                                              int* __restrict__ tokens,
                                              float* __restrict__ scores,
                                              int* __restrict__ fin_tok,
                                              float* __restrict__ fin_sc,
                                              int step) {
    const int sent = blockIdx.x;
    const int tid = threadIdx.x;
    const int rN = (step == 0) ? 1 : BEAM_N;
    __shared__ float bval[64]; __shared__ int bflat[64];
    if (tid < 16 * rN) {
        const int r = tid >> 4, j = tid & 15;
        const int row = sent * BEAM_N + r;
        const float rm = rmax[row], rl = rlse[row];
        const float prev = (step == 0) ? 0.f : scores[row * SLEN_N + step - 1];
        const float xv = cand_x[row * 16 + j];
        const int   tk = cand_ix[row * 16 + j];
        bval[tid]  = ((xv - rm) - rl) + prev;   // exact ref association
        bflat[tid] = r * VOCAB_N + tk;
    }
    __syncthreads();
    __shared__ float cand_sc[8]; __shared__ int cand_flat[8];
    if (tid == 0) {
        const int nC = 16 * rN;
        for (int pass = 0; pass < 8; ++pass) {
            float bv = SENTV; int bi = 0x7fffffff; int bs = -1;
            for (int k = 0; k < nC; ++k) {
                const float v = bval[k]; const int ix = bflat[k];
                if (v > bv || (v == bv && ix < bi)) { bv = v; bi = ix; bs = k; }
            }
            cand_sc[pass] = bv; cand_flat[pass] = bi;
            bval[bs] = SENTV; bflat[bs] = 0x7fffffff;
        }
    }
    __syncthreads();

    __shared__ int   cur_tok[BEAM_N * L_N];
    __shared__ int   cur_fin[BEAM_N * L_N];
    __shared__ float cur_sc[BEAM_N * SLEN_N];
    for (int e = tid; e < BEAM_N * L_N; e += 256) {
        cur_tok[e] = tokens[sent * (BEAM_N * L_N) + e];
        cur_fin[e] = fin_tok[sent * (BEAM_N * L_N) + e];
    }
    for (int e = tid; e < BEAM_N * SLEN_N; e += 256)
        cur_sc[e] = scores[sent * (BEAM_N * SLEN_N) + e];
    __syncthreads();

    __shared__ int   tmp_fin[BEAM_N * L_N];
    __shared__ int   tmp_tok[BEAM_N * L_N];
    __shared__ float tmp_sc[BEAM_N * SLEN_N];
    __shared__ float nfin_s[BEAM_N];
    if (tid == 0) {
        int cb[8], ct[8];
#pragma unroll
        for (int j = 0; j < 8; ++j) {
            cb[j] = cand_flat[j] / VOCAB_N;
            ct[j] = cand_flat[j] % VOCAB_N;
        }
        float allsc[8];
#pragma unroll
        for (int j = 0; j < 4; ++j) allsc[j] = fin_sc[sent * BEAM_N + j];
#pragma unroll
        for (int j = 0; j < 4; ++j)
            allsc[4 + j] = (ct[j] == EOS_T) ? (cand_sc[j] / (float)(step + 1)) : NEGV;
        int fsel[4]; float nfin[4];
        bool used[8] = {false,false,false,false,false,false,false,false};
#pragma unroll
        for (int b = 0; b < 4; ++b) {
            int best = -1; float bvv = 0.f;
#pragma unroll
            for (int j = 0; j < 8; ++j) {
                if (used[j]) continue;
                if (best < 0 || allsc[j] > bvv) { best = j; bvv = allsc[j]; }
            }
            used[best] = true; fsel[b] = best; nfin[b] = bvv;
        }
#pragma unroll
        for (int b = 0; b < 4; ++b) {
            const int s = fsel[b];
            if (s < 4) {
                for (int p = 0; p < L_N; ++p) tmp_fin[b * L_N + p] = cur_fin[s * L_N + p];
            } else {
                const int bm = cb[s - 4];
                for (int p = 0; p < L_N; ++p)
                    tmp_fin[b * L_N + p] = (p == step + 1) ? EOS_T : cur_tok[bm * L_N + p];
            }
        }
        int ab[4], atk[4]; float asc[4]; int na = 0;
#pragma unroll
        for (int j = 0; j < 8; ++j) {
            if (na < 4 && ct[j] != EOS_T) { ab[na] = cb[j]; atk[na] = ct[j]; asc[na] = cand_sc[j]; ++na; }
        }
#pragma unroll
        for (int b = 0; b < 4; ++b) {
            const int bm = ab[b];
            for (int p = 0; p < L_N; ++p)
                tmp_tok[b * L_N + p] = (p == step + 1) ? atk[b] : cur_tok[bm * L_N + p];
            for (int p = 0; p < SLEN_N; ++p)
                tmp_sc[b * SLEN_N + p] = (p == step) ? asc[b] : cur_sc[bm * SLEN_N + p];
        }
#pragma unroll
        for (int b = 0; b < 4; ++b) nfin_s[b] = nfin[b];
    }
    __syncthreads();

    for (int e = tid; e < BEAM_N * L_N; e += 256) {
        fin_tok[sent * (BEAM_N * L_N) + e] = tmp_fin[e];
        tokens[sent * (BEAM_N * L_N) + e]  = tmp_tok[e];
    }
    for (int e = tid; e < BEAM_N * SLEN_N; e += 256)
        scores[sent * (BEAM_N * SLEN_N) + e] = tmp_sc[e];
    if (tid < 4) fin_sc[sent * BEAM_N + tid] = nfin_s[tid];
}

// ---------------- final forced-EOS merge + output write ----------------
__global__ __launch_bounds__(256) void k_final(const float* __restrict__ logits,
                                               const float* __restrict__ rmax,
                                               const float* __restrict__ rlse,
                                               const int* __restrict__ tokens,
                                               const float* __restrict__ scores,
                                               const int* __restrict__ fin_tok,
                                               const float* __restrict__ fin_sc,
                                               float* __restrict__ out) {
    const int sent = blockIdx.x;
    const int tid = threadIdx.x;
    __shared__ int fsel_s[4]; __shared__ float nfin_s[4];
    if (tid == 0) {
        float allsc[8];
#pragma unroll
        for (int r = 0; r < 4; ++r) {
            const int row = sent * BEAM_N + r;
            const float lpE = ((logits[(size_t)row * NPAD + EOS_T] - rmax[row]) - rlse[row]);
            allsc[r] = fin_sc[sent * BEAM_N + r];
            allsc[4 + r] = (scores[row * SLEN_N + (MAXLEN_N - 1)] + lpE) / 65.0f;
        }
        bool used[8] = {false,false,false,false,false,false,false,false};
#pragma unroll
        for (int b = 0; b < 4; ++b) {
            int best = -1; float bvv = 0.f;
#pragma unroll
            for (int j = 0; j < 8; ++j) {
                if (used[j]) continue;
                if (best < 0 || allsc[j] > bvv) { best = j; bvv = allsc[j]; }
            }
            used[best] = true; fsel_s[b] = best; nfin_s[b] = bvv;
        }
    }
    __syncthreads();
    for (int e = tid; e < BEAM_N * L_N; e += 256) {
        const int b = e / L_N, p = e % L_N;
        const int s = fsel_s[b]; int valt;
        if (s < 4) {
            valt = fin_tok[(sent * BEAM_N + s) * L_N + p];
        } else {
            const int r = s - 4;
            valt = (p == MAXLEN_N + 1) ? EOS_T : tokens[(sent * BEAM_N + r) * L_N + p];
        }
        out[(size_t)(sent * BEAM_N + b) * L_N + p] = (float)valt;
    }
    if (tid < 4) out[BSZ_N * BEAM_N * L_N + sent * BEAM_N + tid] = nfin_s[tid];
}

extern "C" void kernel_launch(void* const* d_in, const int* in_sizes, int n_in,
                              void* d_out, int out_size, void* d_ws, size_t ws_size,
                              hipStream_t stream) {
    const float* emb = (const float*)d_in[0];
    const float* W   = (const float*)d_in[1];
    const float* pos = (const float*)d_in[2];
    float* out = (float*)d_out;

    char* w = (char*)d_ws;
    float* logits = (float*)w;  w += (size_t)BB * NPAD * 4;       // 25.76 MB
    float* rmaxb  = (float*)w;  w += BB * 4;
    float* rlseb  = (float*)w;  w += BB * 4;
    int*   tokens = (int*)w;    w += BB * L_N * 4;
    float* scores = (float*)w;  w += BB * SLEN_N * 4;
    int*   ftok   = (int*)w;    w += BB * L_N * 4;
    float* fsc    = (float*)w;  w += BB * 4;
    float* candx  = (float*)w;  w += BB * 16 * 4;
    int*   candix = (int*)w;    w += BB * 16 * 4;

    k_init<<<32, 256, 0, stream>>>(tokens, scores, ftok, fsc);
    for (int s = 0; s < MAXLEN_N; ++s) {
        k_gemm<<<NPAD / 128, 256, 0, stream>>>(W, emb, pos, tokens, logits, s);
        k_rowtop<<<BB, RT_THR, 0, stream>>>(logits, candx, candix, rmaxb, rlseb);
        k_beam<<<BSZ_N, 256, 0, stream>>>(candx, candix, rmaxb, rlseb, tokens, scores, ftok, fsc, s);
    }
    k_gemm<<<NPAD / 128, 256, 0, stream>>>(W, emb, pos, tokens, logits, MAXLEN_N);
    k_rowtop<<<BB, RT_THR, 0, stream>>>(logits, candx, candix, rmaxb, rlseb);
    k_final<<<BSZ_N, 256, 0, stream>>>(logits, rmaxb, rlseb, tokens, scores, ftok, fsc, out);
}

// Round 8
// 32121.637 us; speedup vs baseline: 2.7509x; 2.7509x over previous
//
#include <hip/hip_runtime.h>
#include <cstdint>
#include <cstddef>

#define VOCAB_N 50257
#define NPAD    50304          // padded row stride for logits (393 * 128)
#define DIM     1024
#define BSZ_N   32
#define BEAM_N  4
#define BB      128            // BSZ * BEAM
#define L_N     66             // MAXLEN + 2
#define SLEN_N  65             // MAXLEN + 1
#define MAXLEN_N 64
#define PAD_T   1
#define EOS_T   2
#define NEGV    (-1e9f)
#define SENTV   (-3.402823466e38f)
#define PW_BLOCK 128

// ---------------- compile-time numpy pairwise_sum tree ----------------
struct PWTree {
    int nleaf, nint, maxlev, root;
    int lstart[1024], lnum[1024], lslot[1024];
    int eL[1024], eR[1024], eD[1024];
    int lvl[32];
};

constexpr PWTree build_tree() {
    PWTree t{};
    int fs[64] = {}, fn[64] = {}, fstt[64] = {}, fls[64] = {}, fll[64] = {};
    int tL[1024] = {}, tR[1024] = {}, tD[1024] = {}, tLev[1024] = {};
    int sp = 0, lc = 0, nc = 0, cnt = 0;
    fs[0] = 0; fn[0] = VOCAB_N; fstt[0] = 0; sp = 1;
    int retslot = -1, retlev = 0;
    while (sp > 0) {
        const int n = fn[sp - 1], s = fs[sp - 1], st = fstt[sp - 1];
        if (n <= PW_BLOCK) {
            t.lstart[lc] = s; t.lnum[lc] = n; t.lslot[lc] = cnt;
            retslot = cnt; retlev = 0; ++cnt; ++lc; --sp; continue;
        }
        int L = (n >> 1); L -= (L & 7);
        if (st == 0)      { fstt[sp - 1] = 1; fs[sp] = s;     fn[sp] = L;     fstt[sp] = 0; ++sp; }
        else if (st == 1) { fls[sp - 1] = retslot; fll[sp - 1] = retlev; fstt[sp - 1] = 2;
                            fs[sp] = s + L; fn[sp] = n - L; fstt[sp] = 0; ++sp; }
        else {
            const int lv = (fll[sp - 1] > retlev ? fll[sp - 1] : retlev) + 1;
            tL[nc] = fls[sp - 1]; tR[nc] = retslot; tD[nc] = cnt; tLev[nc] = lv;
            retslot = cnt; retlev = lv; ++cnt; ++nc; --sp;
        }
    }
    int maxlev = 0;
    for (int j = 0; j < nc; ++j) if (tLev[j] > maxlev) maxlev = tLev[j];
    int cl[40] = {};
    for (int j = 0; j < nc; ++j) cl[tLev[j]]++;
    int acc = 0;
    for (int v = 1; v <= maxlev; ++v) { t.lvl[v] = acc; acc += cl[v]; }
    t.lvl[maxlev + 1] = acc;
    int pos[40] = {};
    for (int v = 1; v <= maxlev; ++v) pos[v] = t.lvl[v];
    for (int j = 0; j < nc; ++j) {
        const int v = tLev[j]; const int p = pos[v]++;
        t.eL[p] = tL[j]; t.eR[p] = tR[j]; t.eD[p] = tD[j];
    }
    t.nleaf = lc; t.nint = nc; t.maxlev = maxlev; t.root = retslot;
    return t;
}

__device__ constexpr PWTree g_tree = build_tree();

// ---------------- init state ----------------
__global__ void k_init(int* __restrict__ tokens, float* __restrict__ scores,
                       int* __restrict__ fin_tok, float* __restrict__ fin_sc) {
    int i = blockIdx.x * blockDim.x + threadIdx.x;
    int st = gridDim.x * blockDim.x;
    for (int k = i; k < BB * L_N; k += st) tokens[k] = ((k % L_N) == 0) ? EOS_T : PAD_T;
    for (int k = i; k < BB * SLEN_N; k += st) scores[k] = 0.f;
    for (int k = i; k < BB * L_N; k += st) fin_tok[k] = 0;
    for (int k = i; k < BB; k += st) fin_sc[k] = NEGV;
}

// ---------------- GEMM 128x128 tile, 8x8/thread, W-reg-prefetch dbuf (r1-certified chain) ----------------
#define KSTEP 16
__global__ __launch_bounds__(256) void k_gemm(const float* __restrict__ W,
                                              const float* __restrict__ emb,
                                              const float* __restrict__ pos_emb,
                                              const int* __restrict__ tokens,
                                              float* __restrict__ logits, int step) {
    __shared__ __align__(16) float Hs[2][KSTEP][128];    // 16 KB
    __shared__ __align__(16) float WsP[2][KSTEP][192];   // 24 KB: 16 groups x 8 floats @ stride 12
    const int tid = threadIdx.x;
    const int n0 = blockIdx.x * 128;
    const int cg  = tid & 15;          // col group (8 cols)
    const int m8  = (tid >> 4) * 8;    // row group (8 rows)
    const int c12 = cg * 12;
    const int lr  = tid >> 4;          // k-row for W staging
    const int mH  = tid >> 1;          // H staging row
    const int j0  = (tid & 1) * 8;     // H staging k-offset
    const int tokH = tokens[mH * L_N + step];
    const float* eprow = emb + (size_t)tokH * DIM;
    const float* pprow = pos_emb + (size_t)step * DIM;
    const int nb = n0 + cg * 8;
    const bool full = (n0 + 128 <= VOCAB_N);

    float acc[8][8];
#pragma unroll
    for (int i = 0; i < 8; ++i)
#pragma unroll
        for (int j = 0; j < 8; ++j) acc[i][j] = 0.f;

    float4 wA, wB;    // W prefetch registers (only 8 VGPRs live across compute)

    // ---- prologue: tile 0 ----
    {
        const float* wp = W + (size_t)lr * VOCAB_N + nb;
        if (full) { wA = *(const float4*)wp; wB = *(const float4*)(wp + 4); }
        else {
            wA.x = (nb + 0 < VOCAB_N) ? wp[0] : 0.f;
            wA.y = (nb + 1 < VOCAB_N) ? wp[1] : 0.f;
            wA.z = (nb + 2 < VOCAB_N) ? wp[2] : 0.f;
            wA.w = (nb + 3 < VOCAB_N) ? wp[3] : 0.f;
            wB.x = (nb + 4 < VOCAB_N) ? wp[4] : 0.f;
            wB.y = (nb + 5 < VOCAB_N) ? wp[5] : 0.f;
            wB.z = (nb + 6 < VOCAB_N) ? wp[6] : 0.f;
            wB.w = (nb + 7 < VOCAB_N) ? wp[7] : 0.f;
        }
        *(float4*)&WsP[0][lr][c12]     = wA;
        *(float4*)&WsP[0][lr][c12 + 4] = wB;
        const float4 e0 = *(const float4*)(eprow + j0), e1 = *(const float4*)(eprow + j0 + 4);
        const float4 p0 = *(const float4*)(pprow + j0), p1 = *(const float4*)(pprow + j0 + 4);
        Hs[0][j0 + 0][mH] = e0.x + p0.x; Hs[0][j0 + 1][mH] = e0.y + p0.y;
        Hs[0][j0 + 2][mH] = e0.z + p0.z; Hs[0][j0 + 3][mH] = e0.w + p0.w;
        Hs[0][j0 + 4][mH] = e1.x + p1.x; Hs[0][j0 + 5][mH] = e1.y + p1.y;
        Hs[0][j0 + 6][mH] = e1.z + p1.z; Hs[0][j0 + 7][mH] = e1.w + p1.w;
    }
    __syncthreads();

    const int NT = DIM / KSTEP;   // 64 K-tiles
    for (int t = 0; t < NT; ++t) {
        const int cur = t & 1;
        // ---- issue next W tile's global loads early (HBM latency hides under FMAs) ----
        if (t + 1 < NT) {
            const float* wp = W + (size_t)((t + 1) * KSTEP + lr) * VOCAB_N + nb;
            if (full) { wA = *(const float4*)wp; wB = *(const float4*)(wp + 4); }
            else {
                wA.x = (nb + 0 < VOCAB_N) ? wp[0] : 0.f;
                wA.y = (nb + 1 < VOCAB_N) ? wp[1] : 0.f;
                wA.z = (nb + 2 < VOCAB_N) ? wp[2] : 0.f;
                wA.w = (nb + 3 < VOCAB_N) ? wp[3] : 0.f;
                wB.x = (nb + 4 < VOCAB_N) ? wp[4] : 0.f;
                wB.y = (nb + 5 < VOCAB_N) ? wp[5] : 0.f;
                wB.z = (nb + 6 < VOCAB_N) ? wp[6] : 0.f;
                wB.w = (nb + 7 < VOCAB_N) ? wp[7] : 0.f;
            }
        }
        // ---- compute on LDS[cur] ----
#pragma unroll
        for (int kk = 0; kk < KSTEP; ++kk) {
            const float4 w0 = *(const float4*)&WsP[cur][kk][c12];
            const float4 w1 = *(const float4*)&WsP[cur][kk][c12 + 4];
            const float4 h0 = *(const float4*)&Hs[cur][kk][m8];
            const float4 h1 = *(const float4*)&Hs[cur][kk][m8 + 4];
            const float hh[8] = {h0.x, h0.y, h0.z, h0.w, h1.x, h1.y, h1.z, h1.w};
            const float ww[8] = {w0.x, w0.y, w0.z, w0.w, w1.x, w1.y, w1.z, w1.w};
#pragma unroll
            for (int i = 0; i < 8; ++i)
#pragma unroll
                for (int j = 0; j < 8; ++j)
                    acc[i][j] += hh[i] * ww[j];     // k-ascending f32 FMA chain (certified)
        }
        // ---- stage next tile into the other buffer (H from L2-hot rows, scoped regs) ----
        if (t + 1 < NT) {
            const int nxt = cur ^ 1;
            *(float4*)&WsP[nxt][lr][c12]     = wA;
            *(float4*)&WsP[nxt][lr][c12 + 4] = wB;
            const int k0n = (t + 1) * KSTEP;
            const float4 e0 = *(const float4*)(eprow + k0n + j0);
            const float4 e1 = *(const float4*)(eprow + k0n + j0 + 4);
            const float4 p0 = *(const float4*)(pprow + k0n + j0);
            const float4 p1 = *(const float4*)(pprow + k0n + j0 + 4);
            Hs[nxt][j0 + 0][mH] = e0.x + p0.x; Hs[nxt][j0 + 1][mH] = e0.y + p0.y;
            Hs[nxt][j0 + 2][mH] = e0.z + p0.z; Hs[nxt][j0 + 3][mH] = e0.w + p0.w;
            Hs[nxt][j0 + 4][mH] = e1.x + p1.x; Hs[nxt][j0 + 5][mH] = e1.y + p1.y;
            Hs[nxt][j0 + 6][mH] = e1.z + p1.z; Hs[nxt][j0 + 7][mH] = e1.w + p1.w;
        }
        __syncthreads();
    }
#pragma unroll
    for (int i = 0; i < 8; ++i) {
        float4 o0; o0.x = acc[i][0]; o0.y = acc[i][1]; o0.z = acc[i][2]; o0.w = acc[i][3];
        float4 o1; o1.x = acc[i][4]; o1.y = acc[i][5]; o1.z = acc[i][6]; o1.w = acc[i][7];
        float* dst = &logits[(size_t)(m8 + i) * NPAD + nb];
        *(float4*)dst = o0;
        *(float4*)(dst + 4) = o1;
    }
}

// ---------------- packed (x, idx) keys: strict total order, stable ties ----------------
__device__ __forceinline__ unsigned sortable_f32(float x) {
    unsigned u = __float_as_uint(x);
    return (u & 0x80000000u) ? ~u : (u | 0x80000000u);
}
__device__ __forceinline__ float unsort_f32(unsigned s) {
    unsigned u = (s & 0x80000000u) ? (s & 0x7fffffffu) : ~s;
    return __uint_as_float(u);
}
__device__ __forceinline__ unsigned long long pack_key(float x, int tk) {
    return ((unsigned long long)sortable_f32(x) << 32) | (unsigned)(VOCAB_N - tk);
}
__device__ __forceinline__ void insk16(unsigned long long k, unsigned long long lst[16]) {
#pragma unroll
    for (int p = 0; p < 16; ++p) {
        if (k > lst[p]) { unsigned long long o = lst[p]; lst[p] = k; k = o; }
    }
}
__device__ __forceinline__ unsigned long long wave_max_u64(unsigned long long v) {
#pragma unroll
    for (int o = 32; o > 0; o >>= 1) {
        unsigned long long w = __shfl_xor(v, o, 64);
        if (w > v) v = w;
    }
    return v;
}

// ---------------- per-row: top16 (excl PAD) + max (incl PAD) + numpy-exact pairwise LSE ----------------
#define RT_THR 512
__global__ __launch_bounds__(RT_THR) void k_rowtop(const float* __restrict__ logits,
                                                   float* __restrict__ cand_x,
                                                   int* __restrict__ cand_ix,
                                                   float* __restrict__ rmax,
                                                   float* __restrict__ rlse) {
    const int row = blockIdx.x, tid = threadIdx.x;
    const int lane = tid & 63, wid = tid >> 6;   // 8 waves
    const float* x = logits + (size_t)row * NPAD;

    // ---- scan: per-thread top-16 (excluding PAD) + running max (including PAD) ----
    unsigned long long lst[16];
#pragma unroll
    for (int p = 0; p < 16; ++p) lst[p] = 0ULL;
    float mAll = SENTV;
    for (int v = tid * 4; v + 3 < VOCAB_N; v += RT_THR * 4) {
        const float4 t = *(const float4*)(x + v);
        mAll = fmaxf(mAll, fmaxf(fmaxf(t.x, t.y), fmaxf(t.z, t.w)));
        const float va[4] = {t.x, t.y, t.z, t.w};
#pragma unroll
        for (int u = 0; u < 4; ++u) {
            const int tk = v + u;
            if (tk == PAD_T) continue;
            const unsigned long long key = pack_key(va[u], tk);
            if (key > lst[15]) insk16(key, lst);
        }
    }
    if (tid == 0) {
        const int tk = VOCAB_N - 1;
        mAll = fmaxf(mAll, x[tk]);
        const unsigned long long key = pack_key(x[tk], tk);
        if (key > lst[15]) insk16(key, lst);
    }

    // ---- block max (includes PAD) ----
#pragma unroll
    for (int o = 32; o > 0; o >>= 1) mAll = fmaxf(mAll, __shfl_xor(mAll, o, 64));
    __shared__ float smx[8];
    if (lane == 0) smx[wid] = mAll;

    // ---- stage 1: per-wave top-16 via shfl tournament (no barriers) ----
    __shared__ unsigned long long wtop[8][16];
    for (int pass = 0; pass < 16; ++pass) {
        const unsigned long long cand = lst[0];
        const unsigned long long mx = wave_max_u64(cand);
        const unsigned long long ball = __ballot(cand == mx);
        const int first = __ffsll((unsigned long long)ball) - 1;
        if (lane == first) {
#pragma unroll
            for (int p = 0; p < 15; ++p) lst[p] = lst[p + 1];
            lst[15] = 0ULL;
        }
        if (lane == 0) wtop[wid][pass] = mx;
    }
    __syncthreads();

    // ---- stage 2: wave 0 merges 8x16 = 128 keys -> global top-16 ----
    __shared__ unsigned long long sfin[16];
    if (tid < 64) {
        unsigned long long a = wtop[tid >> 3][(tid & 7) * 2];      // descending pair: a >= b
        unsigned long long b = wtop[tid >> 3][(tid & 7) * 2 + 1];
        for (int pass = 0; pass < 16; ++pass) {
            const unsigned long long mx = wave_max_u64(a);
            const unsigned long long ball = __ballot(a == mx);
            const int first = __ffsll((unsigned long long)ball) - 1;
            if (tid == first) { a = b; b = 0ULL; }
            if (tid == 0) sfin[pass] = mx;
        }
    }
    __syncthreads();
    const float mrow = fmaxf(fmaxf(fmaxf(smx[0], smx[1]), fmaxf(smx[2], smx[3])),
                             fmaxf(fmaxf(smx[4], smx[5]), fmaxf(smx[6], smx[7])));

    // ---- numpy pairwise exp-sum via compile-time tree (bit-exact r3/r4 structure) ----
    __shared__ float slot[2048];
    const int nleaf = g_tree.nleaf, maxlev = g_tree.maxlev;
    for (int leaf = tid; leaf < nleaf; leaf += RT_THR) {
        const int s = g_tree.lstart[leaf];
        const int n = g_tree.lnum[leaf];
        float res;
        if (n < 8) {
            res = 0.f;
            for (int i = 0; i < n; ++i) res += expf(x[s + i] - mrow);
        } else {
            float r0 = expf(x[s + 0] - mrow), r1 = expf(x[s + 1] - mrow);
            float r2 = expf(x[s + 2] - mrow), r3 = expf(x[s + 3] - mrow);
            float r4 = expf(x[s + 4] - mrow), r5 = expf(x[s + 5] - mrow);
            float r6 = expf(x[s + 6] - mrow), r7 = expf(x[s + 7] - mrow);
            int i = 8;
            const int lim = n - (n & 7);
            for (; i < lim; i += 8) {
                r0 += expf(x[s + i + 0] - mrow); r1 += expf(x[s + i + 1] - mrow);
                r2 += expf(x[s + i + 2] - mrow); r3 += expf(x[s + i + 3] - mrow);
                r4 += expf(x[s + i + 4] - mrow); r5 += expf(x[s + i + 5] - mrow);
                r6 += expf(x[s + i + 6] - mrow); r7 += expf(x[s + i + 7] - mrow);
            }
            res = ((r0 + r1) + (r2 + r3)) + ((r4 + r5) + (r6 + r7));
            for (; i < n; ++i) res += expf(x[s + i] - mrow);
        }
        slot[g_tree.lslot[leaf]] = res;
    }
    __syncthreads();
    for (int lev = 1; lev <= maxlev; ++lev) {
        for (int j = g_tree.lvl[lev] + tid; j < g_tree.lvl[lev + 1]; j += RT_THR)
            slot[g_tree.eD[j]] = slot[g_tree.eL[j]] + slot[g_tree.eR[j]];
        __syncthreads();
    }
    if (tid == 0) {
        rmax[row] = mrow;
        rlse[row] = (float)log((double)slot[g_tree.root]);
    }
    if (tid < 16) {
        const unsigned long long k = sfin[tid];
        cand_x[row * 16 + tid]  = unsort_f32((unsigned)(k >> 32));
        cand_ix[row * 16 + tid] = VOCAB_N - (int)(k & 0xFFFFFFFFu);
    }
}

// ---------------- per-sentence: candidate vals + top-8 + literal bookkeeping ----------------
__global__ __launch_bounds__(256) void k_beam(const float* __restrict__ cand_x,
                                              const int* __restrict__ cand_ix,
                                              const float* __restrict__ rmax,
                                              const float* __restrict__ rlse,
                                              int* __restrict__ tokens,
                                              float* __restrict__ scores,
                                              int* __restrict__ fin_tok,
                                              float* __restrict__ fin_sc,
                                              int step) {
    const int sent = blockIdx.x;
    const int tid = threadIdx.x;
    const int rN = (step == 0) ? 1 : BEAM_N;
    __shared__ float bval[64]; __shared__ int bflat[64];
    if (tid < 16 * rN) {
        const int r = tid >> 4, j = tid & 15;
        const int row = sent * BEAM_N + r;
        const float rm = rmax[row], rl = rlse[row];
        const float prev = (step == 0) ? 0.f : scores[row * SLEN_N + step - 1];
        const float xv = cand_x[row * 16 + j];
        const int   tk = cand_ix[row * 16 + j];
        bval[tid]  = ((xv - rm) - rl) + prev;   // exact ref association
        bflat[tid] = r * VOCAB_N + tk;
    }
    __syncthreads();
    __shared__ float cand_sc[8]; __shared__ int cand_flat[8];
    if (tid == 0) {
        const int nC = 16 * rN;
        for (int pass = 0; pass < 8; ++pass) {
            float bv = SENTV; int bi = 0x7fffffff; int bs = -1;
            for (int k = 0; k < nC; ++k) {
                const float v = bval[k]; const int ix = bflat[k];
                if (v > bv || (v == bv && ix < bi)) { bv = v; bi = ix; bs = k; }
            }
            cand_sc[pass] = bv; cand_flat[pass] = bi;
            bval[bs] = SENTV; bflat[bs] = 0x7fffffff;
        }
    }
    __syncthreads();

    __shared__ int   cur_tok[BEAM_N * L_N];
    __shared__ int   cur_fin[BEAM_N * L_N];
    __shared__ float cur_sc[BEAM_N * SLEN_N];
    for (int e = tid; e < BEAM_N * L_N; e += 256) {
        cur_tok[e] = tokens[sent * (BEAM_N * L_N) + e];
        cur_fin[e] = fin_tok[sent * (BEAM_N * L_N) + e];
    }
    for (int e = tid; e < BEAM_N * SLEN_N; e += 256)
        cur_sc[e] = scores[sent * (BEAM_N * SLEN_N) + e];
    __syncthreads();

    __shared__ int   tmp_fin[BEAM_N * L_N];
    __shared__ int   tmp_tok[BEAM_N * L_N];
    __shared__ float tmp_sc[BEAM_N * SLEN_N];
    __shared__ float nfin_s[BEAM_N];
    if (tid == 0) {
        int cb[8], ct[8];
#pragma unroll
        for (int j = 0; j < 8; ++j) {
            cb[j] = cand_flat[j] / VOCAB_N;
            ct[j] = cand_flat[j] % VOCAB_N;
        }
        float allsc[8];
#pragma unroll
        for (int j = 0; j < 4; ++j) allsc[j] = fin_sc[sent * BEAM_N + j];
#pragma unroll
        for (int j = 0; j < 4; ++j)
            allsc[4 + j] = (ct[j] == EOS_T) ? (cand_sc[j] / (float)(step + 1)) : NEGV;
        int fsel[4]; float nfin[4];
        bool used[8] = {false,false,false,false,false,false,false,false};
#pragma unroll
        for (int b = 0; b < 4; ++b) {
            int best = -1; float bvv = 0.f;
#pragma unroll
            for (int j = 0; j < 8; ++j) {
                if (used[j]) continue;
                if (best < 0 || allsc[j] > bvv) { best = j; bvv = allsc[j]; }
            }
            used[best] = true; fsel[b] = best; nfin[b] = bvv;
        }
#pragma unroll
        for (int b = 0; b < 4; ++b) {
            const int s = fsel[b];
            if (s < 4) {
                for (int p = 0; p < L_N; ++p) tmp_fin[b * L_N + p] = cur_fin[s * L_N + p];
            } else {
                const int bm = cb[s - 4];
                for (int p = 0; p < L_N; ++p)
                    tmp_fin[b * L_N + p] = (p == step + 1) ? EOS_T : cur_tok[bm * L_N + p];
            }
        }
        int ab[4], atk[4]; float asc[4]; int na = 0;
#pragma unroll
        for (int j = 0; j < 8; ++j) {
            if (na < 4 && ct[j] != EOS_T) { ab[na] = cb[j]; atk[na] = ct[j]; asc[na] = cand_sc[j]; ++na; }
        }
#pragma unroll
        for (int b = 0; b < 4; ++b) {
            const int bm = ab[b];
            for (int p = 0; p < L_N; ++p)
                tmp_tok[b * L_N + p] = (p == step + 1) ? atk[b] : cur_tok[bm * L_N + p];
            for (int p = 0; p < SLEN_N; ++p)
                tmp_sc[b * SLEN_N + p] = (p == step) ? asc[b] : cur_sc[bm * SLEN_N + p];
        }
#pragma unroll
        for (int b = 0; b < 4; ++b) nfin_s[b] = nfin[b];
    }
    __syncthreads();

    for (int e = tid; e < BEAM_N * L_N; e += 256) {
        fin_tok[sent * (BEAM_N * L_N) + e] = tmp_fin[e];
        tokens[sent * (BEAM_N * L_N) + e]  = tmp_tok[e];
    }
    for (int e = tid; e < BEAM_N * SLEN_N; e += 256)
        scores[sent * (BEAM_N * SLEN_N) + e] = tmp_sc[e];
    if (tid < 4) fin_sc[sent * BEAM_N + tid] = nfin_s[tid];
}

// ---------------- final forced-EOS merge + output write ----------------
__global__ __launch_bounds__(256) void k_final(const float* __restrict__ logits,
                                               const float* __restrict__ rmax,
                                               const float* __restrict__ rlse,
                                               const int* __restrict__ tokens,
                                               const float* __restrict__ scores,
                                               const int* __restrict__ fin_tok,
                                               const float* __restrict__ fin_sc,
                                               float* __restrict__ out) {
    const int sent = blockIdx.x;
    const int tid = threadIdx.x;
    __shared__ int fsel_s[4]; __shared__ float nfin_s[4];
    if (tid == 0) {
        float allsc[8];
#pragma unroll
        for (int r = 0; r < 4; ++r) {
            const int row = sent * BEAM_N + r;
            const float lpE = ((logits[(size_t)row * NPAD + EOS_T] - rmax[row]) - rlse[row]);
            allsc[r] = fin_sc[sent * BEAM_N + r];
            allsc[4 + r] = (scores[row * SLEN_N + (MAXLEN_N - 1)] + lpE) / 65.0f;
        }
        bool used[8] = {false,false,false,false,false,false,false,false};
#pragma unroll
        for (int b = 0; b < 4; ++b) {
            int best = -1; float bvv = 0.f;
#pragma unroll
            for (int j = 0; j < 8; ++j) {
                if (used[j]) continue;
                if (best < 0 || allsc[j] > bvv) { best = j; bvv = allsc[j]; }
            }
            used[best] = true; fsel_s[b] = best; nfin_s[b] = bvv;
        }
    }
    __syncthreads();
    for (int e = tid; e < BEAM_N * L_N; e += 256) {
        const int b = e / L_N, p = e % L_N;
        const int s = fsel_s[b]; int valt;
        if (s < 4) {
            valt = fin_tok[(sent * BEAM_N + s) * L_N + p];
        } else {
            const int r = s - 4;
            valt = (p == MAXLEN_N + 1) ? EOS_T : tokens[(sent * BEAM_N + r) * L_N + p];
        }
        out[(size_t)(sent * BEAM_N + b) * L_N + p] = (float)valt;
    }
    if (tid < 4) out[BSZ_N * BEAM_N * L_N + sent * BEAM_N + tid] = nfin_s[tid];
}

extern "C" void kernel_launch(void* const* d_in, const int* in_sizes, int n_in,
                              void* d_out, int out_size, void* d_ws, size_t ws_size,
                              hipStream_t stream) {
    const float* emb = (const float*)d_in[0];
    const float* W   = (const float*)d_in[1];
    const float* pos = (const float*)d_in[2];
    float* out = (float*)d_out;

    char* w = (char*)d_ws;
    float* logits = (float*)w;  w += (size_t)BB * NPAD * 4;       // 25.76 MB
    float* rmaxb  = (float*)w;  w += BB * 4;
    float* rlseb  = (float*)w;  w += BB * 4;
    int*   tokens = (int*)w;    w += BB * L_N * 4;
    float* scores = (float*)w;  w += BB * SLEN_N * 4;
    int*   ftok   = (int*)w;    w += BB * L_N * 4;
    float* fsc    = (float*)w;  w += BB * 4;
    float* candx  = (float*)w;  w += BB * 16 * 4;
    int*   candix = (int*)w;    w += BB * 16 * 4;

    k_init<<<32, 256, 0, stream>>>(tokens, scores, ftok, fsc);
    for (int s = 0; s < MAXLEN_N; ++s) {
        k_gemm<<<NPAD / 128, 256, 0, stream>>>(W, emb, pos, tokens, logits, s);
        k_rowtop<<<BB, RT_THR, 0, stream>>>(logits, candx, candix, rmaxb, rlseb);
        k_beam<<<BSZ_N, 256, 0, stream>>>(candx, candix, rmaxb, rlseb, tokens, scores, ftok, fsc, s);
    }
    k_gemm<<<NPAD / 128, 256, 0, stream>>>(W, emb, pos, tokens, logits, MAXLEN_N);
    k_rowtop<<<BB, RT_THR, 0, stream>>>(logits, candx, candix, rmaxb, rlseb);
    k_final<<<BSZ_N, 256, 0, stream>>>(logits, rmaxb, rlseb, tokens, scores, ftok, fsc, out);
}

// Round 9
// 21150.096 us; speedup vs baseline: 4.1780x; 1.5187x over previous
//
#include <hip/hip_runtime.h>
#include <cstdint>
#include <cstddef>

#define VOCAB_N 50257
#define NPAD    50304          // padded row stride for logits (393 * 128)
#define DIM     1024
#define BSZ_N   32
#define BEAM_N  4
#define BB      128            // BSZ * BEAM
#define L_N     66             // MAXLEN + 2
#define SLEN_N  65             // MAXLEN + 1
#define MAXLEN_N 64
#define PAD_T   1
#define EOS_T   2
#define NEGV    (-1e9f)
#define SENTV   (-3.402823466e38f)
#define PW_BLOCK 128
#define HSPLIT  25128          // numpy tree root split: L=(50257>>1)-((50257>>1)&7)

typedef unsigned long long u64;

// ---------------- compile-time numpy pairwise_sum sub-trees ----------------
struct PWTree {
    int nleaf, nint, maxlev, root;
    int lstart[512], lnum[512], lslot[512];
    int eL[512], eR[512], eD[512];
    int lvl[32];
};

constexpr PWTree build_tree(int start, int n0) {
    PWTree t{};
    int fs[64] = {}, fn[64] = {}, fstt[64] = {}, fls[64] = {}, fll[64] = {};
    int tL[512] = {}, tR[512] = {}, tD[512] = {}, tLev[512] = {};
    int sp = 0, lc = 0, nc = 0, cnt = 0;
    fs[0] = start; fn[0] = n0; fstt[0] = 0; sp = 1;
    int retslot = -1, retlev = 0;
    while (sp > 0) {
        const int n = fn[sp - 1], s = fs[sp - 1], st = fstt[sp - 1];
        if (n <= PW_BLOCK) {
            t.lstart[lc] = s; t.lnum[lc] = n; t.lslot[lc] = cnt;
            retslot = cnt; retlev = 0; ++cnt; ++lc; --sp; continue;
        }
        int L = (n >> 1); L -= (L & 7);
        if (st == 0)      { fstt[sp - 1] = 1; fs[sp] = s;     fn[sp] = L;     fstt[sp] = 0; ++sp; }
        else if (st == 1) { fls[sp - 1] = retslot; fll[sp - 1] = retlev; fstt[sp - 1] = 2;
                            fs[sp] = s + L; fn[sp] = n - L; fstt[sp] = 0; ++sp; }
        else {
            const int lv = (fll[sp - 1] > retlev ? fll[sp - 1] : retlev) + 1;
            tL[nc] = fls[sp - 1]; tR[nc] = retslot; tD[nc] = cnt; tLev[nc] = lv;
            retslot = cnt; retlev = lv; ++cnt; ++nc; --sp;
        }
    }
    int maxlev = 0;
    for (int j = 0; j < nc; ++j) if (tLev[j] > maxlev) maxlev = tLev[j];
    int cl[40] = {};
    for (int j = 0; j < nc; ++j) cl[tLev[j]]++;
    int acc = 0;
    for (int v = 1; v <= maxlev; ++v) { t.lvl[v] = acc; acc += cl[v]; }
    t.lvl[maxlev + 1] = acc;
    int pos[40] = {};
    for (int v = 1; v <= maxlev; ++v) pos[v] = t.lvl[v];
    for (int j = 0; j < nc; ++j) {
        const int v = tLev[j]; const int p = pos[v]++;
        t.eL[p] = tL[j]; t.eR[p] = tR[j]; t.eD[p] = tD[j];
    }
    t.nleaf = lc; t.nint = nc; t.maxlev = maxlev; t.root = retslot;
    return t;
}

__device__ constexpr PWTree g_treeL = build_tree(0, HSPLIT);
__device__ constexpr PWTree g_treeR = build_tree(HSPLIT, VOCAB_N - HSPLIT);

// ---------------- init state ----------------
__global__ void k_init(int* __restrict__ tokens, float* __restrict__ scores,
                       int* __restrict__ fin_tok, float* __restrict__ fin_sc) {
    int i = blockIdx.x * blockDim.x + threadIdx.x;
    int st = gridDim.x * blockDim.x;
    for (int k = i; k < BB * L_N; k += st) tokens[k] = ((k % L_N) == 0) ? EOS_T : PAD_T;
    for (int k = i; k < BB * SLEN_N; k += st) scores[k] = 0.f;
    for (int k = i; k < BB * L_N; k += st) fin_tok[k] = 0;
    for (int k = i; k < BB; k += st) fin_sc[k] = NEGV;
}

// ---------------- GEMM 128x128 tile, 512 threads, 8x4/thread (r1-certified chain) ----------------
#define KSTEP 16
__global__ __launch_bounds__(512) void k_gemm(const float* __restrict__ W,
                                              const float* __restrict__ emb,
                                              const float* __restrict__ pos_emb,
                                              const int* __restrict__ tokens,
                                              float* __restrict__ logits, int step) {
    __shared__ __align__(16) float Hs[KSTEP][128];    // 8 KB
    __shared__ __align__(16) float WsP[KSTEP][192];   // 12 KB: 16 groups x 8 floats @ stride 12
    const int tid = threadIdx.x;
    const int n0 = blockIdx.x * 128;
    const int cg  = tid & 31;           // col group (4 cols)
    const int m8  = (tid >> 5) * 8;     // row group (8 rows)
    const int wAddr = (cg >> 1) * 12 + (cg & 1) * 4;   // padded W offset for this col group
    const int mH  = tid >> 2;           // H staging row (0..127)
    const int j0  = (tid & 3) * 4;      // H staging k-offset
    const int tokH = tokens[mH * L_N + step];
    const float* eprow = emb + (size_t)tokH * DIM;
    const float* pprow = pos_emb + (size_t)step * DIM;
    const int nb = n0 + cg * 4;
    const bool full = (n0 + 128 <= VOCAB_N);

    float acc[8][4];
#pragma unroll
    for (int i = 0; i < 8; ++i)
#pragma unroll
        for (int j = 0; j < 4; ++j) acc[i][j] = 0.f;

    for (int k0 = 0; k0 < DIM; k0 += KSTEP) {
        // stage W tile rows k0..k0+15, cols n0..n0+127 (each thread one float4)
        {
            const float* wp = W + (size_t)(k0 + (tid >> 5)) * VOCAB_N + nb;
            float4 a;
            if (full) {
                a = *(const float4*)wp;
            } else {
                a.x = (nb + 0 < VOCAB_N) ? wp[0] : 0.f;
                a.y = (nb + 1 < VOCAB_N) ? wp[1] : 0.f;
                a.z = (nb + 2 < VOCAB_N) ? wp[2] : 0.f;
                a.w = (nb + 3 < VOCAB_N) ? wp[3] : 0.f;
            }
            *(float4*)&WsP[tid >> 5][wAddr] = a;
        }
        // stage H tile from emb+pos (identical single-rounded values as gather)
        {
            const float4 e0 = *(const float4*)(eprow + k0 + j0);
            const float4 p0 = *(const float4*)(pprow + k0 + j0);
            Hs[j0 + 0][mH] = e0.x + p0.x;
            Hs[j0 + 1][mH] = e0.y + p0.y;
            Hs[j0 + 2][mH] = e0.z + p0.z;
            Hs[j0 + 3][mH] = e0.w + p0.w;
        }
        __syncthreads();
#pragma unroll
        for (int kk = 0; kk < KSTEP; ++kk) {
            const float4 wv = *(const float4*)&WsP[kk][wAddr];
            const float4 h0 = *(const float4*)&Hs[kk][m8];
            const float4 h1 = *(const float4*)&Hs[kk][m8 + 4];
            const float hh[8] = {h0.x, h0.y, h0.z, h0.w, h1.x, h1.y, h1.z, h1.w};
            const float ww[4] = {wv.x, wv.y, wv.z, wv.w};
#pragma unroll
            for (int i = 0; i < 8; ++i)
#pragma unroll
                for (int j = 0; j < 4; ++j)
                    acc[i][j] += hh[i] * ww[j];     // k-ascending f32 FMA chain (certified)
        }
        __syncthreads();
    }
#pragma unroll
    for (int i = 0; i < 8; ++i) {
        float4 o; o.x = acc[i][0]; o.y = acc[i][1]; o.z = acc[i][2]; o.w = acc[i][3];
        *(float4*)&logits[(size_t)(m8 + i) * NPAD + nb] = o;
    }
}

// ---------------- packed (x, idx) keys: strict total order, stable ties ----------------
__device__ __forceinline__ unsigned sortable_f32(float x) {
    unsigned u = __float_as_uint(x);
    return (u & 0x80000000u) ? ~u : (u | 0x80000000u);
}
__device__ __forceinline__ float unsort_f32(unsigned s) {
    unsigned u = (s & 0x80000000u) ? (s & 0x7fffffffu) : ~s;
    return __uint_as_float(u);
}
__device__ __forceinline__ u64 pack_key(float x, int tk) {
    return ((u64)sortable_f32(x) << 32) | (unsigned)(VOCAB_N - tk);
}
__device__ __forceinline__ void insk16(u64 k, u64 lst[16]) {
#pragma unroll
    for (int p = 0; p < 16; ++p) {
        if (k > lst[p]) { u64 o = lst[p]; lst[p] = k; k = o; }
    }
}
__device__ __forceinline__ u64 wave_max_u64(u64 v) {
#pragma unroll
    for (int o = 32; o > 0; o >>= 1) {
        u64 w = __shfl_xor(v, o, 64);
        if (w > v) v = w;
    }
    return v;
}

// ---------------- pass 1: per half-row max (incl PAD) + top-16 (excl PAD) ----------------
#define RT_THR 512
__global__ __launch_bounds__(RT_THR) void k_rowscan(const float* __restrict__ logits,
                                                    float* __restrict__ halfmax,
                                                    u64* __restrict__ htop) {
    const int hb = blockIdx.x;            // 0..255
    const int row = hb >> 1, half = hb & 1;
    const int tid = threadIdx.x;
    const int lane = tid & 63, wid = tid >> 6;   // 8 waves
    const float* x = logits + (size_t)row * NPAD;
    const int lo = half ? HSPLIT : 0;
    const int hi = half ? VOCAB_N : HSPLIT;

    u64 lst[16];
#pragma unroll
    for (int p = 0; p < 16; ++p) lst[p] = 0ULL;
    float mAll = SENTV;
    for (int v = lo + tid * 4; v + 3 < hi; v += RT_THR * 4) {
        const float4 t = *(const float4*)(x + v);
        mAll = fmaxf(mAll, fmaxf(fmaxf(t.x, t.y), fmaxf(t.z, t.w)));
        const float va[4] = {t.x, t.y, t.z, t.w};
#pragma unroll
        for (int u = 0; u < 4; ++u) {
            const int tk = v + u;
            if (tk == PAD_T) continue;
            const u64 key = pack_key(va[u], tk);
            if (key > lst[15]) insk16(key, lst);
        }
    }
    if (half == 1 && tid == 0) {          // tail element 50256
        const int tk = VOCAB_N - 1;
        mAll = fmaxf(mAll, x[tk]);
        const u64 key = pack_key(x[tk], tk);
        if (key > lst[15]) insk16(key, lst);
    }

    // wave max
#pragma unroll
    for (int o = 32; o > 0; o >>= 1) mAll = fmaxf(mAll, __shfl_xor(mAll, o, 64));
    __shared__ float smx[8];
    if (lane == 0) smx[wid] = mAll;

    // per-wave top-16 tournament
    __shared__ u64 wtop[8][16];
    for (int pass = 0; pass < 16; ++pass) {
        const u64 cand = lst[0];
        const u64 mx = wave_max_u64(cand);
        const u64 ball = __ballot(cand == mx);
        const int first = __ffsll((u64)ball) - 1;
        if (lane == first) {
#pragma unroll
            for (int p = 0; p < 15; ++p) lst[p] = lst[p + 1];
            lst[15] = 0ULL;
        }
        if (lane == 0) wtop[wid][pass] = mx;
    }
    __syncthreads();

    // wave 0 merges 8x16 = 128 keys -> top-16
    __shared__ u64 sfin[16];
    if (tid < 64) {
        u64 a = wtop[tid >> 3][(tid & 7) * 2];      // descending pair: a >= b
        u64 b = wtop[tid >> 3][(tid & 7) * 2 + 1];
        for (int pass = 0; pass < 16; ++pass) {
            const u64 mx = wave_max_u64(a);
            const u64 ball = __ballot(a == mx);
            const int first = __ffsll((u64)ball) - 1;
            if (tid == first) { a = b; b = 0ULL; }
            if (tid == 0) sfin[pass] = mx;
        }
    }
    __syncthreads();
    if (tid == 0)
        halfmax[hb] = fmaxf(fmaxf(fmaxf(smx[0], smx[1]), fmaxf(smx[2], smx[3])),
                            fmaxf(fmaxf(smx[4], smx[5]), fmaxf(smx[6], smx[7])));
    if (tid < 16) htop[hb * 16 + tid] = sfin[tid];
}

// ---------------- pass 2: numpy-exact pairwise exp-sum over the half sub-tree ----------------
__global__ __launch_bounds__(RT_THR) void k_rowexp(const float* __restrict__ logits,
                                                   const float* __restrict__ halfmax,
                                                   float* __restrict__ halfsum) {
    const int hb = blockIdx.x;
    const int row = hb >> 1, half = hb & 1;
    const int tid = threadIdx.x;
    const float* x = logits + (size_t)row * NPAD;
    const float mrow = fmaxf(halfmax[row * 2], halfmax[row * 2 + 1]);   // whole-row max
    const PWTree& T = half ? g_treeR : g_treeL;

    __shared__ float slot[1024];
    for (int leaf = tid; leaf < T.nleaf; leaf += RT_THR) {
        const int s = T.lstart[leaf];
        const int n = T.lnum[leaf];
        float res;
        if (n < 8) {
            res = 0.f;
            for (int i = 0; i < n; ++i) res += expf(x[s + i] - mrow);
        } else {
            float r0 = expf(x[s + 0] - mrow), r1 = expf(x[s + 1] - mrow);
            float r2 = expf(x[s + 2] - mrow), r3 = expf(x[s + 3] - mrow);
            float r4 = expf(x[s + 4] - mrow), r5 = expf(x[s + 5] - mrow);
            float r6 = expf(x[s + 6] - mrow), r7 = expf(x[s + 7] - mrow);
            int i = 8;
            const int lim = n - (n & 7);
            for (; i < lim; i += 8) {
                r0 += expf(x[s + i + 0] - mrow); r1 += expf(x[s + i + 1] - mrow);
                r2 += expf(x[s + i + 2] - mrow); r3 += expf(x[s + i + 3] - mrow);
                r4 += expf(x[s + i + 4] - mrow); r5 += expf(x[s + i + 5] - mrow);
                r6 += expf(x[s + i + 6] - mrow); r7 += expf(x[s + i + 7] - mrow);
            }
            res = ((r0 + r1) + (r2 + r3)) + ((r4 + r5) + (r6 + r7));
            for (; i < n; ++i) res += expf(x[s + i] - mrow);
        }
        slot[T.lslot[leaf]] = res;
    }
    __syncthreads();
    for (int lev = 1; lev <= T.maxlev; ++lev) {
        for (int j = T.lvl[lev] + tid; j < T.lvl[lev + 1]; j += RT_THR)
            slot[T.eD[j]] = slot[T.eL[j]] + slot[T.eR[j]];
        __syncthreads();
    }
    if (tid == 0) halfsum[hb] = slot[T.root];
}

// ---------------- per-sentence: merge halves + top-8 + literal bookkeeping ----------------
__global__ __launch_bounds__(256) void k_beam(const u64* __restrict__ htop,
                                              const float* __restrict__ halfmax,
                                              const float* __restrict__ halfsum,
                                              int* __restrict__ tokens,
                                              float* __restrict__ scores,
                                              int* __restrict__ fin_tok,
                                              float* __restrict__ fin_sc,
                                              int step) {
    const int sent = blockIdx.x;
    const int tid = threadIdx.x;
    const int rN = (step == 0) ? 1 : BEAM_N;

    // load 4 rows x 2 halves x 16 keys
    __shared__ u64 keys[4][32];
    for (int e = tid; e < 128; e += 256) {
        const int r = e >> 5, i = e & 31;
        keys[r][i] = htop[((sent * BEAM_N + r) * 2 + (i >> 4)) * 16 + (i & 15)];
    }
    __syncthreads();

    // two-pointer merge of the two desc-sorted 16-lists -> row top-16 (keys strictly distinct)
    __shared__ u64 merged[4][16];
    if (tid < 4) {
        int ia = 0, ib = 0;
        for (int o = 0; o < 16; ++o) {
            const u64 a = (ia < 16) ? keys[tid][ia] : 0ULL;
            const u64 b = (ib < 16) ? keys[tid][16 + ib] : 0ULL;
            const bool ta = a > b;
            merged[tid][o] = ta ? a : b;
            ia += ta ? 1 : 0; ib += ta ? 0 : 1;
        }
    }
    __syncthreads();

    __shared__ float bval[64]; __shared__ int bflat[64];
    if (tid < 16 * rN) {
        const int r = tid >> 4, j = tid & 15;
        const int row = sent * BEAM_N + r;
        const float rm = fmaxf(halfmax[row * 2], halfmax[row * 2 + 1]);
        const float rl = (float)log((double)(halfsum[row * 2] + halfsum[row * 2 + 1]));
        const float prev = (step == 0) ? 0.f : scores[row * SLEN_N + step - 1];
        const u64 k = merged[r][j];
        const float xv = unsort_f32((unsigned)(k >> 32));
        const int   tk = VOCAB_N - (int)(k & 0xFFFFFFFFu);
        bval[tid]  = ((xv - rm) - rl) + prev;   // exact ref association
        bflat[tid] = r * VOCAB_N + tk;
    }
    __syncthreads();
    __shared__ float cand_sc[8]; __shared__ int cand_flat[8];
    if (tid == 0) {
        const int nC = 16 * rN;
        for (int pass = 0; pass < 8; ++pass) {
            float bv = SENTV; int bi = 0x7fffffff; int bs = -1;
            for (int k = 0; k < nC; ++k) {
                const float v = bval[k]; const int ix = bflat[k];
                if (v > bv || (v == bv && ix < bi)) { bv = v; bi = ix; bs = k; }
            }
            cand_sc[pass] = bv; cand_flat[pass] = bi;
            bval[bs] = SENTV; bflat[bs] = 0x7fffffff;
        }
    }
    __syncthreads();

    __shared__ int   cur_tok[BEAM_N * L_N];
    __shared__ int   cur_fin[BEAM_N * L_N];
    __shared__ float cur_sc[BEAM_N * SLEN_N];
    for (int e = tid; e < BEAM_N * L_N; e += 256) {
        cur_tok[e] = tokens[sent * (BEAM_N * L_N) + e];
        cur_fin[e] = fin_tok[sent * (BEAM_N * L_N) + e];
    }
    for (int e = tid; e < BEAM_N * SLEN_N; e += 256)
        cur_sc[e] = scores[sent * (BEAM_N * SLEN_N) + e];
    __syncthreads();

    __shared__ int   tmp_fin[BEAM_N * L_N];
    __shared__ int   tmp_tok[BEAM_N * L_N];
    __shared__ float tmp_sc[BEAM_N * SLEN_N];
    __shared__ float nfin_s[BEAM_N];
    if (tid == 0) {
        int cb[8], ct[8];
#pragma unroll
        for (int j = 0; j < 8; ++j) {
            cb[j] = cand_flat[j] / VOCAB_N;
            ct[j] = cand_flat[j] % VOCAB_N;
        }
        float allsc[8];
#pragma unroll
        for (int j = 0; j < 4; ++j) allsc[j] = fin_sc[sent * BEAM_N + j];
#pragma unroll
        for (int j = 0; j < 4; ++j)
            allsc[4 + j] = (ct[j] == EOS_T) ? (cand_sc[j] / (float)(step + 1)) : NEGV;
        int fsel[4]; float nfin[4];
        bool used[8] = {false,false,false,false,false,false,false,false};
#pragma unroll
        for (int b = 0; b < 4; ++b) {
            int best = -1; float bvv = 0.f;
#pragma unroll
            for (int j = 0; j < 8; ++j) {
                if (used[j]) continue;
                if (best < 0 || allsc[j] > bvv) { best = j; bvv = allsc[j]; }
            }
            used[best] = true; fsel[b] = best; nfin[b] = bvv;
        }
#pragma unroll
        for (int b = 0; b < 4; ++b) {
            const int s = fsel[b];
            if (s < 4) {
                for (int p = 0; p < L_N; ++p) tmp_fin[b * L_N + p] = cur_fin[s * L_N + p];
            } else {
                const int bm = cb[s - 4];
                for (int p = 0; p < L_N; ++p)
                    tmp_fin[b * L_N + p] = (p == step + 1) ? EOS_T : cur_tok[bm * L_N + p];
            }
        }
        int ab[4], atk[4]; float asc[4]; int na = 0;
#pragma unroll
        for (int j = 0; j < 8; ++j) {
            if (na < 4 && ct[j] != EOS_T) { ab[na] = cb[j]; atk[na] = ct[j]; asc[na] = cand_sc[j]; ++na; }
        }
#pragma unroll
        for (int b = 0; b < 4; ++b) {
            const int bm = ab[b];
            for (int p = 0; p < L_N; ++p)
                tmp_tok[b * L_N + p] = (p == step + 1) ? atk[b] : cur_tok[bm * L_N + p];
            for (int p = 0; p < SLEN_N; ++p)
                tmp_sc[b * SLEN_N + p] = (p == step) ? asc[b] : cur_sc[bm * SLEN_N + p];
        }
#pragma unroll
        for (int b = 0; b < 4; ++b) nfin_s[b] = nfin[b];
    }
    __syncthreads();

    for (int e = tid; e < BEAM_N * L_N; e += 256) {
        fin_tok[sent * (BEAM_N * L_N) + e] = tmp_fin[e];
        tokens[sent * (BEAM_N * L_N) + e]  = tmp_tok[e];
    }
    for (int e = tid; e < BEAM_N * SLEN_N; e += 256)
        scores[sent * (BEAM_N * SLEN_N) + e] = tmp_sc[e];
    if (tid < 4) fin_sc[sent * BEAM_N + tid] = nfin_s[tid];
}

// ---------------- final forced-EOS merge + output write ----------------
__global__ __launch_bounds__(256) void k_final(const float* __restrict__ logits,
                                               const float* __restrict__ halfmax,
                                               const float* __restrict__ halfsum,
                                               const int* __restrict__ tokens,
                                               const float* __restrict__ scores,
                                               const int* __restrict__ fin_tok,
                                               const float* __restrict__ fin_sc,
                                               float* __restrict__ out) {
    const int sent = blockIdx.x;
    const int tid = threadIdx.x;
    __shared__ int fsel_s[4]; __shared__ float nfin_s[4];
    if (tid == 0) {
        float allsc[8];
#pragma unroll
        for (int r = 0; r < 4; ++r) {
            const int row = sent * BEAM_N + r;
            const float rm = fmaxf(halfmax[row * 2], halfmax[row * 2 + 1]);
            const float rl = (float)log((double)(halfsum[row * 2] + halfsum[row * 2 + 1]));
            const float lpE = ((logits[(size_t)row * NPAD + EOS_T] - rm) - rl);
            allsc[r] = fin_sc[sent * BEAM_N + r];
            allsc[4 + r] = (scores[row * SLEN_N + (MAXLEN_N - 1)] + lpE) / 65.0f;
        }
        bool used[8] = {false,false,false,false,false,false,false,false};
#pragma unroll
        for (int b = 0; b < 4; ++b) {
            int best = -1; float bvv = 0.f;
#pragma unroll
            for (int j = 0; j < 8; ++j) {
                if (used[j]) continue;
                if (best < 0 || allsc[j] > bvv) { best = j; bvv = allsc[j]; }
            }
            used[best] = true; fsel_s[b] = best; nfin_s[b] = bvv;
        }
    }
    __syncthreads();
    for (int e = tid; e < BEAM_N * L_N; e += 256) {
        const int b = e / L_N, p = e % L_N;
        const int s = fsel_s[b]; int valt;
        if (s < 4) {
            valt = fin_tok[(sent * BEAM_N + s) * L_N + p];
        } else {
            const int r = s - 4;
            valt = (p == MAXLEN_N + 1) ? EOS_T : tokens[(sent * BEAM_N + r) * L_N + p];
        }
        out[(size_t)(sent * BEAM_N + b) * L_N + p] = (float)valt;
    }
    if (tid < 4) out[BSZ_N * BEAM_N * L_N + sent * BEAM_N + tid] = nfin_s[tid];
}

extern "C" void kernel_launch(void* const* d_in, const int* in_sizes, int n_in,
                              void* d_out, int out_size, void* d_ws, size_t ws_size,
                              hipStream_t stream) {
    const float* emb = (const float*)d_in[0];
    const float* W   = (const float*)d_in[1];
    const float* pos = (const float*)d_in[2];
    float* out = (float*)d_out;

    char* w = (char*)d_ws;
    float* logits  = (float*)w;  w += (size_t)BB * NPAD * 4;       // 25.76 MB
    float* halfmax = (float*)w;  w += BB * 2 * 4;
    float* halfsum = (float*)w;  w += BB * 2 * 4;
    u64*   htop    = (u64*)w;    w += (size_t)BB * 2 * 16 * 8;     // 32 KB
    int*   tokens  = (int*)w;    w += BB * L_N * 4;
    float* scores  = (float*)w;  w += BB * SLEN_N * 4;
    int*   ftok    = (int*)w;    w += BB * L_N * 4;
    float* fsc     = (float*)w;  w += BB * 4;

    k_init<<<32, 256, 0, stream>>>(tokens, scores, ftok, fsc);
    for (int s = 0; s < MAXLEN_N; ++s) {
        k_gemm<<<NPAD / 128, 512, 0, stream>>>(W, emb, pos, tokens, logits, s);
        k_rowscan<<<BB * 2, RT_THR, 0, stream>>>(logits, halfmax, htop);
        k_rowexp<<<BB * 2, RT_THR, 0, stream>>>(logits, halfmax, halfsum);
        k_beam<<<BSZ_N, 256, 0, stream>>>(htop, halfmax, halfsum, tokens, scores, ftok, fsc, s);
    }
    k_gemm<<<NPAD / 128, 512, 0, stream>>>(W, emb, pos, tokens, logits, MAXLEN_N);
    k_rowscan<<<BB * 2, RT_THR, 0, stream>>>(logits, halfmax, htop);
    k_rowexp<<<BB * 2, RT_THR, 0, stream>>>(logits, halfmax, halfsum);
    k_final<<<BSZ_N, 256, 0, stream>>>(logits, halfmax, halfsum, tokens, scores, ftok, fsc, out);
}